// Round 8
// baseline (83.991 us; speedup 1.0000x reference)
//
#include <hip/hip_runtime.h>
#include <hip/hip_fp16.h>
#include <cstdint>

#define VOCAB 50000
#define EMB   300
#define SEQ   80
#define HID   128
#define BATCH 4096

typedef __attribute__((ext_vector_type(8))) _Float16 f16x8;
typedef __attribute__((ext_vector_type(4))) float    f32x4;

static __device__ __forceinline__ float fast_tanh(float xv) {
    const float e = __expf(2.f * xv);
    float r;
    asm("v_rcp_f32 %0, %1" : "=v"(r) : "v"(e + 1.f));
    return fmaf(-2.f, r, 1.f);
}
static __device__ __forceinline__ float f16b2f(unsigned short u) {
    _Float16 h; __builtin_memcpy(&h, &u, 2); return (float)h;
}
static __device__ __forceinline__ unsigned pack2h(float a, float b) {
    _Float16 ha = (_Float16)a, hb = (_Float16)b;
    unsigned short ua, ub;
    __builtin_memcpy(&ua, &ha, 2); __builtin_memcpy(&ub, &hb, 2);
    return (unsigned)ua | ((unsigned)ub << 16);
}

// ---------------------------------------------------------------------------
// k_wprep: fragment-ordered fp16 Wxh table. chunk c=(ks,col,g):
//   W2[c][j] = fp16(Wxh[32ks+8g+j][col]), zero-padded past K=300. 80 KB.
// ---------------------------------------------------------------------------
__global__ __launch_bounds__(256) void k_wprep(const float* __restrict__ Wxh,
                                               _Float16* __restrict__ W2) {
    const int c = blockIdx.x * 256 + threadIdx.x;   // 0..5119
    if (c >= 5120) return;
    const int ks = c >> 9, rem = c & 511, col = rem >> 2, g = rem & 3;
    f16x8 f;
    #pragma unroll
    for (int j = 0; j < 8; ++j) {
        const int k = 32 * ks + 8 * g + j;
        f[j] = (_Float16)(k < EMB ? Wxh[k * HID + col] : 0.f);
    }
    *reinterpret_cast<f16x8*>(W2 + (size_t)c * 8) = f;
}

// ---------------------------------------------------------------------------
// k_ptab: P[v][c] = fp16( emb[v] @ Wxh + bh )  [50000 x 128], bh folded in.
// 256 thr / 4 waves, 64 rows/block; wave owns 32 cols. Software pipeline:
// while tile t converts+MFMAs, ALL 20 float4 raw e-loads of tile t+1 are in
// flight (launch_bounds(256,2) -> ~220 VGPR allowed). emb is L3-resident.
// ---------------------------------------------------------------------------
__global__ __launch_bounds__(256, 2) void k_ptab(
    const float*    __restrict__ emb,  // [VOCAB][300]
    const _Float16* __restrict__ W2,   // frag table
    const float*    __restrict__ bh,   // [128]
    _Float16*       __restrict__ P)    // [VOCAB][128]
{
    __shared__ __align__(16) unsigned char Ps[16 * 256];   // 4 KB

    const int tid = threadIdx.x, lane = tid & 63, wv = tid >> 6;
    const int r16 = lane & 15, g = lane >> 4;
    const int v0 = blockIdx.x * 64;

    f16x8 wa[10], wb[10];
    #pragma unroll
    for (int ks = 0; ks < 10; ++ks) {
        const int colA = 32 * wv + r16;
        wa[ks] = *reinterpret_cast<const f16x8*>(W2 + ((size_t)ks * 512 + colA * 4 + g) * 8);
        wb[ks] = *reinterpret_cast<const f16x8*>(W2 + ((size_t)ks * 512 + (colA + 16) * 4 + g) * 8);
    }
    const float4 bhA = *reinterpret_cast<const float4*>(bh + 32 * wv + 4 * g);
    const float4 bhB = *reinterpret_cast<const float4*>(bh + 32 * wv + 16 + 4 * g);

    const int psA = r16 * 256 + (((4 * wv + (g >> 1)) ^ r16) & 15) * 16 + (g & 1) * 8;
    const int psB = r16 * 256 + (((4 * wv + 2 + (g >> 1)) ^ r16) & 15) * 16 + (g & 1) * 8;
    const int srow = tid >> 4, schunk = tid & 15;
    const int sbyte = srow * 256 + ((schunk ^ srow) & 15) * 16;

    float4 u0[10], u1[10];

#define LOADT(TILE)                                                               \
    {                                                                             \
        const float* rp = emb + (size_t)min(v0 + (TILE) * 16 + r16, VOCAB - 1) * EMB; \
        _Pragma("unroll")                                                         \
        for (int ks = 0; ks < 9; ++ks) {                                          \
            u0[ks] = *reinterpret_cast<const float4*>(rp + 32 * ks + 8 * g);      \
            u1[ks] = *reinterpret_cast<const float4*>(rp + 32 * ks + 8 * g + 4);  \
        }                                                                         \
        float4 z = {0.f, 0.f, 0.f, 0.f};                                          \
        u0[9] = (g == 0) ? *reinterpret_cast<const float4*>(rp + 288)             \
              : (g == 1) ? *reinterpret_cast<const float4*>(rp + 296) : z;        \
        u1[9] = (g == 0) ? *reinterpret_cast<const float4*>(rp + 292) : z;        \
    }

    LOADT(0)

    #pragma unroll
    for (int tile = 0; tile < 4; ++tile) {
        // convert raw -> fp16 fragments (frees u0/u1 for the next tile)
        f16x8 ef[10];
        #pragma unroll
        for (int ks = 0; ks < 10; ++ks) {
            f16x8 f;
            f[0] = (_Float16)u0[ks].x; f[1] = (_Float16)u0[ks].y;
            f[2] = (_Float16)u0[ks].z; f[3] = (_Float16)u0[ks].w;
            f[4] = (_Float16)u1[ks].x; f[5] = (_Float16)u1[ks].y;
            f[6] = (_Float16)u1[ks].z; f[7] = (_Float16)u1[ks].w;
            ef[ks] = f;
        }
        // issue next tile's loads now; they fly under the 20 MFMAs below
        if (tile < 3) LOADT(tile + 1)

        f32x4 accA = {0.f, 0.f, 0.f, 0.f}, accB = {0.f, 0.f, 0.f, 0.f};
        #pragma unroll
        for (int ks = 0; ks < 10; ++ks) {
            accA = __builtin_amdgcn_mfma_f32_16x16x32_f16(wa[ks], ef[ks], accA, 0, 0, 0);
            accB = __builtin_amdgcn_mfma_f32_16x16x32_f16(wb[ks], ef[ks], accB, 0, 0, 0);
        }

        uint2 oA, oB;
        oA.x = pack2h(accA[0] + bhA.x, accA[1] + bhA.y);
        oA.y = pack2h(accA[2] + bhA.z, accA[3] + bhA.w);
        oB.x = pack2h(accB[0] + bhB.x, accB[1] + bhB.y);
        oB.y = pack2h(accB[2] + bhB.z, accB[3] + bhB.w);
        *reinterpret_cast<uint2*>(&Ps[psA]) = oA;
        *reinterpret_cast<uint2*>(&Ps[psB]) = oB;
        __syncthreads();

        const int orow = v0 + tile * 16 + srow;
        if (orow < VOCAB)
            *reinterpret_cast<uint4*>(P + (size_t)orow * HID + schunk * 8) =
                *reinterpret_cast<const uint4*>(&Ps[sbyte]);
        __syncthreads();
    }
#undef LOADT
}

// ---------------------------------------------------------------------------
// k_rnn: h(t) = tanh( P[x[b,t]] + h(t-1) @ Whh ). ROWS=8 per block, 256 thr
// (4 waves x 32 cols), grid 512 -> 2 INDEPENDENT blocks/CU (decoupled
// barriers overlap each other's latency chains). xp gathered from P straight
// into the consuming lane's registers (depth-2 prefetch, one 64B sector per
// row per wave) -- no LDS staging for xp. h exchanged via LDS (XOR swizzle).
// Swapped-operand MFMA: mfma(wh, h_frag, acc): D lane (g,r16) reg r =
//   h_new[batch row r16][col base+4g+r]. Rows 8..15 are don't-care (bounded).
// ---------------------------------------------------------------------------
__global__ __launch_bounds__(256, 2) void k_rnn(
    const int*      __restrict__ x,    // [BATCH][SEQ]
    const _Float16* __restrict__ P,    // [VOCAB][128] fp16 (bh folded)
    const float*    __restrict__ Whh,  // [128][128]
    const float*    __restrict__ Wd,   // [128]
    const float*    __restrict__ bd,   // [1]
    float*          __restrict__ out)  // [BATCH]
{
    __shared__ __align__(16) unsigned char Hb[2][16 * 256];  // h fp16, 2 x 4 KB
    __shared__ int xidx[8 * SEQ];

    const int tid = threadIdx.x, lane = tid & 63, wv = tid >> 6;  // wv 0..3
    const int r16 = lane & 15, g = lane >> 4;
    const int rb = blockIdx.x * 8;
    const int r8 = min(r16, 7);         // clamped batch row for gather

    for (int q = tid; q < 8 * SEQ; q += 256) xidx[q] = x[rb * SEQ + q];
    for (int q = tid; q < 512; q += 256) {   // zero BOTH h buffers (8 KB)
        uint4 z = {};
        *reinterpret_cast<uint4*>(&Hb[0][0] + 0) = z;  // placate compiler aliasing
        reinterpret_cast<uint4*>(&Hb[0][0])[q] = z;
    }

    const int cA = 32 * wv + 4 * g;     // first fp16 col of this lane's ct0 slice

    // ---- t-invariant LDS offsets ----
    int h_rd[4];
    #pragma unroll
    for (int ks = 0; ks < 4; ++ks)
        h_rd[ks] = r16 * 256 + (((4 * ks + g) ^ r16) & 15) * 16;
    const int hw0 = r16 * 256 + (((4 * wv + (g >> 1)) ^ r16) & 15) * 16 + (g & 1) * 8;
    const int hw1 = r16 * 256 + (((4 * wv + 2 + (g >> 1)) ^ r16) & 15) * 16 + (g & 1) * 8;

    // ---- Whh B-fragments for the wave's two 16-col tiles ----
    f16x8 wh0[4], wh1[4];
    #pragma unroll
    for (int ks = 0; ks < 4; ++ks) {
        f16x8 f0, f1;
        #pragma unroll
        for (int j = 0; j < 8; ++j) {
            const int k = 32 * ks + 8 * g + j;
            f0[j] = (_Float16)Whh[k * HID + 32 * wv + r16];
            f1[j] = (_Float16)Whh[k * HID + 32 * wv + 16 + r16];
        }
        wh0[ks] = f0; wh1[ks] = f1;
    }

    __syncthreads();  // xidx + zeroed Hb visible

    // ---- depth-2 xp register pipeline: one uint2 (4 fp16 cols) per ct ----
    uint2 xa0, xa1, xb0, xb1;
    {
        const _Float16* p0 = P + (size_t)xidx[r8 * SEQ + 0] * HID + cA;
        xa0 = *reinterpret_cast<const uint2*>(p0);
        xa1 = *reinterpret_cast<const uint2*>(p0 + 16);
        const _Float16* p1 = P + (size_t)xidx[r8 * SEQ + 1] * HID + cA;
        xb0 = *reinterpret_cast<const uint2*>(p1);
        xb1 = *reinterpret_cast<const uint2*>(p1 + 16);
    }

#define STEP(T, PB, CA0, CA1)                                                      \
    {                                                                              \
        f32x4 accA, accB;                                                          \
        accA[0] = f16b2f((unsigned short)(CA0.x & 0xffff));                        \
        accA[1] = f16b2f((unsigned short)(CA0.x >> 16));                           \
        accA[2] = f16b2f((unsigned short)(CA0.y & 0xffff));                        \
        accA[3] = f16b2f((unsigned short)(CA0.y >> 16));                           \
        accB[0] = f16b2f((unsigned short)(CA1.x & 0xffff));                        \
        accB[1] = f16b2f((unsigned short)(CA1.x >> 16));                           \
        accB[2] = f16b2f((unsigned short)(CA1.y & 0xffff));                        \
        accB[3] = f16b2f((unsigned short)(CA1.y >> 16));                           \
        if ((T) + 2 < SEQ) {  /* reissue this reg-set for xp(T+2) */               \
            const _Float16* np = P + (size_t)xidx[r8 * SEQ + (T) + 2] * HID + cA;  \
            CA0 = *reinterpret_cast<const uint2*>(np);                             \
            CA1 = *reinterpret_cast<const uint2*>(np + 16);                        \
        }                                                                          \
        const unsigned char* hb = &Hb[PB][0];                                      \
        const f16x8 h0 = *reinterpret_cast<const f16x8*>(hb + h_rd[0]);            \
        const f16x8 h1 = *reinterpret_cast<const f16x8*>(hb + h_rd[1]);            \
        const f16x8 h2 = *reinterpret_cast<const f16x8*>(hb + h_rd[2]);            \
        const f16x8 h3 = *reinterpret_cast<const f16x8*>(hb + h_rd[3]);            \
        accA = __builtin_amdgcn_mfma_f32_16x16x32_f16(wh0[0], h0, accA, 0, 0, 0);  \
        accB = __builtin_amdgcn_mfma_f32_16x16x32_f16(wh1[0], h0, accB, 0, 0, 0);  \
        accA = __builtin_amdgcn_mfma_f32_16x16x32_f16(wh0[1], h1, accA, 0, 0, 0);  \
        accB = __builtin_amdgcn_mfma_f32_16x16x32_f16(wh1[1], h1, accB, 0, 0, 0);  \
        accA = __builtin_amdgcn_mfma_f32_16x16x32_f16(wh0[2], h2, accA, 0, 0, 0);  \
        accB = __builtin_amdgcn_mfma_f32_16x16x32_f16(wh1[2], h2, accB, 0, 0, 0);  \
        accA = __builtin_amdgcn_mfma_f32_16x16x32_f16(wh0[3], h3, accA, 0, 0, 0);  \
        accB = __builtin_amdgcn_mfma_f32_16x16x32_f16(wh1[3], h3, accB, 0, 0, 0);  \
        unsigned char* hwp = &Hb[(PB) ^ 1][0];                                     \
        uint2 o0, o1;                                                              \
        o0.x = pack2h(fast_tanh(accA[0]), fast_tanh(accA[1]));                     \
        o0.y = pack2h(fast_tanh(accA[2]), fast_tanh(accA[3]));                     \
        o1.x = pack2h(fast_tanh(accB[0]), fast_tanh(accB[1]));                     \
        o1.y = pack2h(fast_tanh(accB[2]), fast_tanh(accB[3]));                     \
        *reinterpret_cast<uint2*>(hwp + hw0) = o0;                                 \
        *reinterpret_cast<uint2*>(hwp + hw1) = o1;                                 \
        asm volatile("s_waitcnt lgkmcnt(0)" ::: "memory");                         \
        __builtin_amdgcn_s_barrier();                                              \
        __builtin_amdgcn_sched_barrier(0);                                         \
    }

    for (int t = 0; t < SEQ; t += 2) {
        STEP(t,     0, xa0, xa1);
        STEP(t + 1, 1, xb0, xb1);
    }
#undef STEP

    // ---- final dense + sigmoid: h(79) in Hb[0]; 32 threads per batch row ----
    const char* hb0 = (const char*)&Hb[0][0];
    const int r = tid >> 5, m = tid & 31;   // r 0..7, cols 4m..4m+3
    const int fb = r * 256 + (((m >> 1) ^ r) & 15) * 16 + (m & 1) * 8;
    const uint2 hv = *reinterpret_cast<const uint2*>(hb0 + fb);
    const float4 wd = *reinterpret_cast<const float4*>(&Wd[4 * m]);
    float part = f16b2f((unsigned short)(hv.x & 0xffff)) * wd.x
               + f16b2f((unsigned short)(hv.x >> 16))    * wd.y
               + f16b2f((unsigned short)(hv.y & 0xffff)) * wd.z
               + f16b2f((unsigned short)(hv.y >> 16))    * wd.w;
    part += __shfl_down(part, 16, 32);
    part += __shfl_down(part, 8, 32);
    part += __shfl_down(part, 4, 32);
    part += __shfl_down(part, 2, 32);
    part += __shfl_down(part, 1, 32);
    if (m == 0) out[rb + r] = 1.f / (1.f + expf(-(part + bd[0])));
}

// ---------------------------------------------------------------------------
extern "C" void kernel_launch(void* const* d_in, const int* in_sizes, int n_in,
                              void* d_out, int out_size, void* d_ws, size_t ws_size,
                              hipStream_t stream)
{
    (void)in_sizes; (void)n_in; (void)out_size; (void)ws_size;
    const int*   x   = (const int*)  d_in[0];
    const float* emb = (const float*)d_in[1];
    const float* Wxh = (const float*)d_in[2];
    const float* Whh = (const float*)d_in[3];
    const float* bh  = (const float*)d_in[4];
    const float* Wd  = (const float*)d_in[5];
    const float* bd  = (const float*)d_in[6];
    float* out = (float*)d_out;

    _Float16* P  = (_Float16*)d_ws;                          // 12.8 MB
    _Float16* W2 = (_Float16*)((char*)d_ws + 12800000);      // 80 KB frag table

    k_wprep<<<20, 256, 0, stream>>>(Wxh, W2);
    k_ptab<<<(VOCAB + 63) / 64, 256, 0, stream>>>(emb, W2, bh, P);
    k_rnn<<<BATCH / 8, 256, 0, stream>>>(x, P, Whh, Wd, bd, out);
}